// Round 17
// baseline (174.152 us; speedup 1.0000x reference)
//
#include <hip/hip_runtime.h>

#define EPSF 1e-5f
#define NSEG 2048
#define NTHR 768     // 12 waves
#define NWAVE 12
#define NBLK 256

typedef short s16x8 __attribute__((ext_vector_type(8)));
typedef float f32x16 __attribute__((ext_vector_type(16)));
typedef unsigned u32;

__device__ __forceinline__ u32 f2bfu(float f) {
  u32 u = __float_as_uint(f);
  u += 0x7FFFu + ((u >> 16) & 1u);  // RNE; no NaN/Inf in data
  return u >> 16;
}
__device__ __forceinline__ u32 pk2(float a, float b) {  // prep path only
  return f2bfu(a) | (f2bfu(b) << 16);
}
// v_cvt_pk_bf16_f32: dst = {lo=bf16(a), hi=bf16(b)} — 1 VALU op
__device__ __forceinline__ u32 cvtpk(float a, float b) {
  u32 r;
  asm("v_cvt_pk_bf16_f32 %0, %1, %2" : "=v"(r) : "v"(a), "v"(b));
  return r;
}

union FragU { s16x8 v; u32 u[4]; };

struct LayerP { const float *W, *b, *g, *be, *m, *v; };

__global__ void zero_kernel(uint4* __restrict__ p, int n16) {
  int i = blockIdx.x * blockDim.x + threadIdx.x;
  if (i < n16) p[i] = make_uint4(0u, 0u, 0u, 0u);
}

// Fold BN into weights (bf16) and biases. Layers 1,2 stored K-PERMUTED by
// chi(s,hi,j) = 32*(s>>1)+16*(s&1)+4*hi+(j<4 ? j : j+4) — the k-order a lane
// naturally holds after the previous layer's MFMA, so no inter-layer exchange.
__global__ void prep_kernel(LayerP p0, LayerP p1, LayerP p2,
                            unsigned short* __restrict__ wsW,
                            float* __restrict__ biasf) {
  const int L = blockIdx.x;
  LayerP p = (L == 0) ? p0 : ((L == 1) ? p1 : p2);
  const int t = threadIdx.x;
  uint2* wdst = (uint2*)(wsW + L * 16384);
  for (int i = 0; i < 8; ++i) {
    int cid = t + i * 256;             // 2048 chunks = 128 rows x 16 chunks(16B)
    int row = cid >> 4, ch = cid & 15;
    float s = p.g[row] * rsqrtf(p.v[row] + EPSF);
    float w[8];
    if (L == 0) {                      // natural order: chunk ch = k 8ch..8ch+7
      const float4* s4 = (const float4*)(p.W + row * 128 + ch * 8);
      float4 a = s4[0], b = s4[1];
      w[0]=a.x; w[1]=a.y; w[2]=a.z; w[3]=a.w; w[4]=b.x; w[5]=b.y; w[6]=b.z; w[7]=b.w;
    } else {                           // chi-permuted: chunk ch = (2s'+hi)
      int sp = ch >> 1, hi = ch & 1;
      int kb = 32 * (sp >> 1) + 16 * (sp & 1) + 4 * hi;
      const float* src = p.W + row * 128;
      w[0]=src[kb+0]; w[1]=src[kb+1]; w[2]=src[kb+2];  w[3]=src[kb+3];
      w[4]=src[kb+8]; w[5]=src[kb+9]; w[6]=src[kb+10]; w[7]=src[kb+11];
    }
    wdst[cid * 2 + 0] = make_uint2(pk2(w[0]*s, w[1]*s), pk2(w[2]*s, w[3]*s));
    wdst[cid * 2 + 1] = make_uint2(pk2(w[4]*s, w[5]*s), pk2(w[6]*s, w[7]*s));
  }
  if (t < 128) {
    float s = p.g[t] * rsqrtf(p.v[t] + EPSF);
    biasf[L * 128 + t] = p.b[t] * s + p.be[t] - p.m[t] * s;
  }
}

// Barrier-free persistent encoder — round-16 datapath (proven best: 105.6us,
// 84 VGPR + 64 AGPR at 3 waves/SIMD, no spill, setprio +4%) plus HALF-TILE
// prefetch: next tile's rows 0..15 (xlo, 32 VGPR — fits the ~106-VGPR budget,
// unlike r15's full 64) are loaded at segment-phase start where frag is dead
// and VGPR liveness is ~30. The hi half (xhi) is issued at tile top and its
// latency hides under the h=0 transpose. Register law (3x confirmed): accs(64
// AGPR) + 64-reg xr can never overlap; 32-reg xlo is the legal version.
// L0/L1: D = W'.h (lane = x-row), k-permuted weights -> no lane exchange.
// L2: operand-swapped mfma(frag, w) -> lane = OUT CHANNEL, rows in regs:
//     segment sum/max reduce in-register, one bpermute, atomics flush.
// LDS: [0,98304) swizzled weights; [98304,147456) 12x4KB transpose regions.
__global__ __launch_bounds__(NTHR) __attribute__((amdgpu_waves_per_eu(3, 3)))
void enc_kernel(const float* __restrict__ x, const int* __restrict__ batch,
                const unsigned short* __restrict__ wsW, const float* __restrict__ biasf,
                float* __restrict__ seg_sum, int* __restrict__ seg_max,
                u32* __restrict__ seg_cnt, int N, int ntiles) {
  __shared__ __attribute__((aligned(16))) unsigned char lds[98304 + NWAVE * 4096];
  __shared__ __attribute__((aligned(16))) float bias_lds[384];
  const int t = threadIdx.x;
  const int lane = t & 63, wv = t >> 6;
  const int l31 = lane & 31, hi = lane >> 5;
  const int swz = l31 & 15;
  const int xaddr = (lane ^ 32) << 2;  // ds_bpermute addr (segment phase only)

  // one-time: stage weights global->LDS with chunk^row swizzle
  {
    const uint4* src = (const uint4*)wsW;
#pragma unroll
    for (int i = 0; i < 8; ++i) {
      int idx = t + i * NTHR;          // 6144 x 16B
      int byte = idx << 4;
      int dst = byte ^ (((byte >> 8) & 15) << 4);  // chunk ^= row&15
      *(uint4*)&lds[dst] = src[idx];
    }
  }
  if (t < 384) bias_lds[t] = biasf[t];
  __syncthreads();                      // the only block barrier

  // L2 bias per-lane (channel cg*32+l31), hoisted out of the tile loop
  float bias2[4];
#pragma unroll
  for (int cg = 0; cg < 4; ++cg) bias2[cg] = bias_lds[256 + cg * 32 + l31];

  const int hbase = 98304 + wv * 4096;
  const float4* x4 = (const float4*)x;

  // contiguous balanced tile range for this wave
  const int w = blockIdx.x * NWAVE + wv;         // 0..3071
  const int TW = NBLK * NWAVE;                   // 3072
  const int base = ntiles / TW, rem = ntiles % TW;
  const int t0 = w * base + (w < rem ? w : rem);
  const int t1 = t0 + base + (w < rem ? 1 : 0);

  float4 xlo[8];                       // persistent lo-half prefetch (32 VGPR)
  int sreg = -1;
  {  // prologue: prefetch tile t0's rows 0..15
    const bool any = (t0 < t1);
    const bool fullp = any && (t0 * 32 + 32 <= N);
    const float4* xt = x4 + (size_t)t0 * 1024 + lane;
#pragma unroll
    for (int i = 0; i < 8; ++i)
      xlo[i] = fullp ? xt[i * 64] : make_float4(0.f, 0.f, 0.f, 0.f);
    int r = t0 * 32 + l31;
    sreg = (any && r < N) ? batch[r] : -1;
  }

  for (int tile = t0; tile < t1; ++tile) {
    const int scur = sreg;
    const bool full = (tile * 32 + 32 <= N);
    const float4* xt = x4 + (size_t)tile * 1024 + lane;

    // issue hi half (rows 16..31) now; latency hides under the h=0 transpose
    float4 xhi[8];
#pragma unroll
    for (int i = 0; i < 8; ++i)
      xhi[i] = full ? xt[(8 + i) * 64] : make_float4(0.f, 0.f, 0.f, 0.f);

    // ---- wave-local transpose: two 16-row halves through the 4KB region ----
    FragU frag[8];
#pragma unroll
    for (int h = 0; h < 2; ++h) {
#pragma unroll
      for (int i = 0; i < 8; ++i) {
        int rowp = 2 * i + hi;           // LDS-local row 0..15 (global row 16h+rowp)
        float4 v = h ? xhi[i] : xlo[i];
        *(uint2*)&lds[hbase + rowp * 256 + ((((l31 >> 1) ^ rowp) << 4)) + (l31 & 1) * 8] =
            make_uint2(cvtpk(v.x, v.y), cvtpk(v.z, v.w));
      }
      if ((l31 >> 4) == h) {             // my row lives in this half
        const int rowp = l31 & 15;
#pragma unroll
        for (int s = 0; s < 8; ++s)
          frag[s].v = *(const s16x8*)&lds[hbase + rowp * 256 + (((2 * s + hi) ^ rowp) << 4)];
      }
    }

    // ---- 3 fused layers (k-permuted weights; no inter-layer exchange) ----
    f32x16 accs[4];
#pragma unroll
    for (int L = 0; L < 3; ++L) {
      const int wb = L * 32768 + l31 * 256;
#pragma unroll
      for (int cg = 0; cg < 4; ++cg) {
        f32x16 z = {0,0,0,0,0,0,0,0,0,0,0,0,0,0,0,0};
        accs[cg] = z;
      }
      __builtin_amdgcn_s_setprio(1);
#pragma unroll
      for (int s = 0; s < 8; ++s) {
#pragma unroll
        for (int cg = 0; cg < 4; ++cg) {
          const s16x8 a =
              *(const s16x8*)&lds[wb + cg * 8192 + (((2 * s + hi) ^ swz) << 4)];
          if (L < 2)
            accs[cg] = __builtin_amdgcn_mfma_f32_32x32x16_bf16(a, frag[s].v, accs[cg], 0, 0, 0);
          else  // swapped: D = h2 . W2'^T, lane = out-channel, rows in regs
            accs[cg] = __builtin_amdgcn_mfma_f32_32x32x16_bf16(frag[s].v, a, accs[cg], 0, 0, 0);
        }
      }
      __builtin_amdgcn_s_setprio(0);
      if (L < 2) {
        // bias + relu, pack straight into next-layer frags (chi k-order)
#pragma unroll
        for (int cg = 0; cg < 4; ++cg) {
          float tr[16];
#pragma unroll
          for (int q = 0; q < 4; ++q) {
            int ch = cg * 32 + 4 * hi + 8 * q;   // C/D: c = (r&3) + 8*(r>>2) + 4*hi
            const float4 bb = *(const float4*)&bias_lds[L * 128 + ch];
            tr[4 * q + 0] = fmaxf(accs[cg][4 * q + 0] + bb.x, 0.f);
            tr[4 * q + 1] = fmaxf(accs[cg][4 * q + 1] + bb.y, 0.f);
            tr[4 * q + 2] = fmaxf(accs[cg][4 * q + 2] + bb.z, 0.f);
            tr[4 * q + 3] = fmaxf(accs[cg][4 * q + 3] + bb.w, 0.f);
          }
#pragma unroll
          for (int kh = 0; kh < 2; ++kh) {
            frag[2 * cg + kh].u[0] = cvtpk(tr[8 * kh + 0], tr[8 * kh + 1]);
            frag[2 * cg + kh].u[1] = cvtpk(tr[8 * kh + 2], tr[8 * kh + 3]);
            frag[2 * cg + kh].u[2] = cvtpk(tr[8 * kh + 4], tr[8 * kh + 5]);
            frag[2 * cg + kh].u[3] = cvtpk(tr[8 * kh + 6], tr[8 * kh + 7]);
          }
        }
      }
    }

    // ---- prefetch next tile's lo half (frag dead; 32 VGPR fits the envelope);
    //      its HBM latency hides under the segment reductions + atomics ----
    __builtin_amdgcn_sched_barrier(0);
    {
      int nt = tile + 1;
      const bool any = (nt < t1);
      const bool fulln = any && (nt * 32 + 32 <= N);
      const float4* xtn = x4 + (size_t)nt * 1024 + lane;
#pragma unroll
      for (int i = 0; i < 8; ++i)
        xlo[i] = fulln ? xtn[i * 64] : make_float4(0.f, 0.f, 0.f, 0.f);
      int r = nt * 32 + l31;
      sreg = (any && r < N) ? batch[r] : -1;
    }
    __builtin_amdgcn_sched_barrier(0);

    // ---- segment phase, in-register (lane = channel cg*32+l31; 16 rows in regs) ----
    // row of accs[cg][rg] (global within tile) = (rg&3) + 8*(rg>>2) + 4*hi
    const int nvalid = min(N - tile * 32, 32);
    const int sid0 = __builtin_amdgcn_readlane(scur, 0);
    const int sidL = __builtin_amdgcn_readlane(scur, nvalid - 1);
#pragma unroll
    for (int cg = 0; cg < 4; ++cg)
#pragma unroll
      for (int rg = 0; rg < 16; ++rg)
        accs[cg][rg] = fmaxf(accs[cg][rg] + bias2[cg], 0.f);

    if (nvalid == 32 && sid0 == sidL) {
      // fast path: whole tile in one segment
#pragma unroll
      for (int cg = 0; cg < 4; ++cg) {
        float s = 0.f, mx = 0.f;
#pragma unroll
        for (int rg = 0; rg < 16; ++rg) { s += accs[cg][rg]; mx = fmaxf(mx, accs[cg][rg]); }
        float ps = __int_as_float(__builtin_amdgcn_ds_bpermute(xaddr, __float_as_int(s)));
        float pm = __int_as_float(__builtin_amdgcn_ds_bpermute(xaddr, __float_as_int(mx)));
        s += ps; mx = fmaxf(mx, pm);
        if (!hi) {
          atomicAdd(&seg_sum[sid0 * 128 + cg * 32 + l31], s);
          atomicMax(&seg_max[sid0 * 128 + cg * 32 + l31], __float_as_int(mx));
        }
      }
      if (lane == 0) atomicAdd(&seg_cnt[sid0], 32u);
    } else {
      // slow path: per-row sids via bpermute, loop over the (small) sid range
      int srow[16];
#pragma unroll
      for (int rg = 0; rg < 16; ++rg) {
        int m = (rg & 3) + 8 * (rg >> 2) + 4 * hi;
        srow[rg] = __builtin_amdgcn_ds_bpermute(m << 2, scur);
      }
      for (int sg = sid0; sg <= sidL; ++sg) {
#pragma unroll
        for (int cg = 0; cg < 4; ++cg) {
          float s = 0.f, mx = 0.f;
#pragma unroll
          for (int rg = 0; rg < 16; ++rg) {
            float v = (srow[rg] == sg) ? accs[cg][rg] : 0.f;
            s += v; mx = fmaxf(mx, v);
          }
          float ps = __int_as_float(__builtin_amdgcn_ds_bpermute(xaddr, __float_as_int(s)));
          float pm = __int_as_float(__builtin_amdgcn_ds_bpermute(xaddr, __float_as_int(mx)));
          s += ps; mx = fmaxf(mx, pm);
          if (!hi) {
            atomicAdd(&seg_sum[sg * 128 + cg * 32 + l31], s);
            atomicMax(&seg_max[sg * 128 + cg * 32 + l31], __float_as_int(mx));
          }
        }
        u32 c = (u32)__popcll(__ballot(hi == 0 && scur == sg));
        if (lane == 0) atomicAdd(&seg_cnt[sg], c);
      }
    }
  }
}

// out[s,o] = BN( [sum|max|mean] @ Wo^T + bo )
__global__ __launch_bounds__(128)
void proj_kernel(const float* __restrict__ seg_sum, const unsigned* __restrict__ seg_max,
                 const u32* __restrict__ seg_cnt,
                 const float* __restrict__ Wo, const float* __restrict__ bo,
                 const float* __restrict__ go, const float* __restrict__ beo,
                 const float* __restrict__ mo, const float* __restrict__ vo,
                 float* __restrict__ out) {
  __shared__ __attribute__((aligned(16))) float agg[384];
  __shared__ float part[64];
  const int s = blockIdx.x, t = threadIdx.x;
  float cinv = 1.f / fmaxf((float)seg_cnt[s], 1.f);
  for (int i = t; i < 384; i += 128) {
    float v;
    if (i < 128)      v = seg_sum[s * 128 + i];
    else if (i < 256) v = __uint_as_float(seg_max[s * 128 + i - 128]);
    else              v = seg_sum[s * 128 + i - 256] * cinv;
    agg[i] = v;
  }
  __syncthreads();
  const int o = t & 63, hf = t >> 6;
  const float4* wrow = (const float4*)(Wo + o * 384 + hf * 192);
  float acc = 0.f;
#pragma unroll 8
  for (int k4 = 0; k4 < 48; ++k4) {
    float4 w = wrow[k4];
    float4 a = *(const float4*)&agg[hf * 192 + k4 * 4];
    acc += w.x * a.x + w.y * a.y + w.z * a.z + w.w * a.w;
  }
  if (hf) part[o] = acc;
  __syncthreads();
  if (!hf) {
    acc += part[o];
    float sc = go[o] * rsqrtf(vo[o] + EPSF);
    out[s * 64 + o] = (acc + bo[o] - mo[o]) * sc + beo[o];
  }
}

extern "C" void kernel_launch(void* const* d_in, const int* in_sizes, int n_in,
                              void* d_out, int out_size, void* d_ws, size_t ws_size,
                              hipStream_t stream) {
  (void)n_in; (void)out_size; (void)ws_size;
  const float* x = (const float*)d_in[0];
  const int* batch = (const int*)d_in[1];
  LayerP P0{(const float*)d_in[2],  (const float*)d_in[3],  (const float*)d_in[4],
            (const float*)d_in[5],  (const float*)d_in[6],  (const float*)d_in[7]};
  LayerP P1{(const float*)d_in[8],  (const float*)d_in[9],  (const float*)d_in[10],
            (const float*)d_in[11], (const float*)d_in[12], (const float*)d_in[13]};
  LayerP P2{(const float*)d_in[14], (const float*)d_in[15], (const float*)d_in[16],
            (const float*)d_in[17], (const float*)d_in[18], (const float*)d_in[19]};
  const float* Wo  = (const float*)d_in[20];
  const float* bo  = (const float*)d_in[21];
  const float* go  = (const float*)d_in[22];
  const float* beo = (const float*)d_in[23];
  const float* mo  = (const float*)d_in[24];
  const float* vo  = (const float*)d_in[25];
  const int N = in_sizes[0] / 128;

  char* ws = (char*)d_ws;
  float* seg_sum = (float*)ws;                         // 1 MiB
  int*   seg_max = (int*)(ws + (1u << 20));            // 1 MiB (float bits, >=0)
  u32*   seg_cnt = (u32*)(ws + (2u << 20));            // 8 KiB
  unsigned short* wsW = (unsigned short*)(ws + (2u << 20) + 8192);  // 96 KiB
  float* biasf = (float*)(ws + (2u << 20) + 8192 + 98304);          // 1.5 KiB

  const int n16 = ((2 << 20) + 8192) / 16;
  zero_kernel<<<(n16 + 255) / 256, 256, 0, stream>>>((uint4*)d_ws, n16);
  prep_kernel<<<3, 256, 0, stream>>>(P0, P1, P2, wsW, biasf);
  const int ntiles = (N + 31) / 32;
  enc_kernel<<<NBLK, NTHR, 0, stream>>>(x, batch, wsW, biasf, seg_sum, seg_max, seg_cnt,
                                        N, ntiles);
  proj_kernel<<<NSEG, 128, 0, stream>>>(seg_sum, (const unsigned*)seg_max, seg_cnt,
                                        Wo, bo, go, beo, mo, vo, (float*)d_out);
}

// Round 18
// 107.325 us; speedup vs baseline: 1.6227x; 1.6227x over previous
//
#include <hip/hip_runtime.h>

#define EPSF 1e-5f
#define NSEG 2048
#define NTHR 768     // 12 waves
#define NWAVE 12
#define NBLK 256

typedef short s16x8 __attribute__((ext_vector_type(8)));
typedef float f32x16 __attribute__((ext_vector_type(16)));
typedef unsigned u32;

__device__ __forceinline__ u32 f2bfu(float f) {
  u32 u = __float_as_uint(f);
  u += 0x7FFFu + ((u >> 16) & 1u);  // RNE; no NaN/Inf in data
  return u >> 16;
}
__device__ __forceinline__ u32 pk2(float a, float b) {  // prep path only
  return f2bfu(a) | (f2bfu(b) << 16);
}
// v_cvt_pk_bf16_f32: dst = {lo=bf16(a), hi=bf16(b)} — 1 VALU op
__device__ __forceinline__ u32 cvtpk(float a, float b) {
  u32 r;
  asm("v_cvt_pk_bf16_f32 %0, %1, %2" : "=v"(r) : "v"(a), "v"(b));
  return r;
}

union FragU { s16x8 v; u32 u[4]; };

struct LayerP { const float *W, *b, *g, *be, *m, *v; };

__global__ void zero_kernel(uint4* __restrict__ p, int n16) {
  int i = blockIdx.x * blockDim.x + threadIdx.x;
  if (i < n16) p[i] = make_uint4(0u, 0u, 0u, 0u);
}

// Fold BN into weights (bf16) and biases. Layers 1,2 stored K-PERMUTED by
// chi(s,hi,j) = 32*(s>>1)+16*(s&1)+4*hi+(j<4 ? j : j+4) — the k-order a lane
// naturally holds after the previous layer's MFMA, so no inter-layer exchange.
__global__ void prep_kernel(LayerP p0, LayerP p1, LayerP p2,
                            unsigned short* __restrict__ wsW,
                            float* __restrict__ biasf) {
  const int L = blockIdx.x;
  LayerP p = (L == 0) ? p0 : ((L == 1) ? p1 : p2);
  const int t = threadIdx.x;
  uint2* wdst = (uint2*)(wsW + L * 16384);
  for (int i = 0; i < 8; ++i) {
    int cid = t + i * 256;             // 2048 chunks = 128 rows x 16 chunks(16B)
    int row = cid >> 4, ch = cid & 15;
    float s = p.g[row] * rsqrtf(p.v[row] + EPSF);
    float w[8];
    if (L == 0) {                      // natural order: chunk ch = k 8ch..8ch+7
      const float4* s4 = (const float4*)(p.W + row * 128 + ch * 8);
      float4 a = s4[0], b = s4[1];
      w[0]=a.x; w[1]=a.y; w[2]=a.z; w[3]=a.w; w[4]=b.x; w[5]=b.y; w[6]=b.z; w[7]=b.w;
    } else {                           // chi-permuted: chunk ch = (2s'+hi)
      int sp = ch >> 1, hi = ch & 1;
      int kb = 32 * (sp >> 1) + 16 * (sp & 1) + 4 * hi;
      const float* src = p.W + row * 128;
      w[0]=src[kb+0]; w[1]=src[kb+1]; w[2]=src[kb+2];  w[3]=src[kb+3];
      w[4]=src[kb+8]; w[5]=src[kb+9]; w[6]=src[kb+10]; w[7]=src[kb+11];
    }
    wdst[cid * 2 + 0] = make_uint2(pk2(w[0]*s, w[1]*s), pk2(w[2]*s, w[3]*s));
    wdst[cid * 2 + 1] = make_uint2(pk2(w[4]*s, w[5]*s), pk2(w[6]*s, w[7]*s));
  }
  if (t < 128) {
    float s = p.g[t] * rsqrtf(p.v[t] + EPSF);
    biasf[L * 128 + t] = p.b[t] * s + p.be[t] - p.m[t] * s;
  }
}

// Barrier-free persistent encoder — EXACT round-16 kernel (proven best: 105.6us,
// 84 VGPR + 64 AGPR at 3 waves/SIMD, no spill; setprio +4%). Register law
// (4x confirmed, incl. r17's 32-reg half-tile attempt): the envelope is exactly
// full — NO cross-tile prefetch of any size fits. Loads at tile top; xr dies at
// the transpose before accs come alive.
// L0/L1: D = W'.h (lane = x-row), k-permuted weights -> no lane exchange.
// L2: operand-swapped mfma(frag, w) -> lane = OUT CHANNEL, rows in regs:
//     segment sum/max reduce in-register, one bpermute, atomics flush.
// LDS: [0,98304) swizzled weights; [98304,147456) 12x4KB transpose regions.
__global__ __launch_bounds__(NTHR) __attribute__((amdgpu_waves_per_eu(3, 3)))
void enc_kernel(const float* __restrict__ x, const int* __restrict__ batch,
                const unsigned short* __restrict__ wsW, const float* __restrict__ biasf,
                float* __restrict__ seg_sum, int* __restrict__ seg_max,
                u32* __restrict__ seg_cnt, int N, int ntiles) {
  __shared__ __attribute__((aligned(16))) unsigned char lds[98304 + NWAVE * 4096];
  __shared__ __attribute__((aligned(16))) float bias_lds[384];
  const int t = threadIdx.x;
  const int lane = t & 63, wv = t >> 6;
  const int l31 = lane & 31, hi = lane >> 5;
  const int swz = l31 & 15;
  const int xaddr = (lane ^ 32) << 2;  // ds_bpermute addr (segment phase only)

  // one-time: stage weights global->LDS with chunk^row swizzle
  {
    const uint4* src = (const uint4*)wsW;
#pragma unroll
    for (int i = 0; i < 8; ++i) {
      int idx = t + i * NTHR;          // 6144 x 16B
      int byte = idx << 4;
      int dst = byte ^ (((byte >> 8) & 15) << 4);  // chunk ^= row&15
      *(uint4*)&lds[dst] = src[idx];
    }
  }
  if (t < 384) bias_lds[t] = biasf[t];
  __syncthreads();                      // the only block barrier

  // L2 bias per-lane (channel cg*32+l31), hoisted out of the tile loop
  float bias2[4];
#pragma unroll
  for (int cg = 0; cg < 4; ++cg) bias2[cg] = bias_lds[256 + cg * 32 + l31];

  const int hbase = 98304 + wv * 4096;
  const float4* x4 = (const float4*)x;

  // contiguous balanced tile range for this wave
  const int w = blockIdx.x * NWAVE + wv;         // 0..3071
  const int TW = NBLK * NWAVE;                   // 3072
  const int base = ntiles / TW, rem = ntiles % TW;
  const int t0 = w * base + (w < rem ? w : rem);
  const int t1 = t0 + base + (w < rem ? 1 : 0);

  for (int tile = t0; tile < t1; ++tile) {
    // ---- coalesced tile load: instr i = bytes [i*1024,(i+1)*1024), lane*16 within ----
    const bool full = (tile * 32 + 32 <= N);
    float4 xr[16];
    {
      const float4* xt = x4 + (size_t)tile * 1024 + lane;
#pragma unroll
      for (int i = 0; i < 16; ++i)
        xr[i] = full ? xt[i * 64] : make_float4(0.f, 0.f, 0.f, 0.f);
    }
    int rr = tile * 32 + l31;
    const int scur = (rr < N) ? batch[rr] : -1;

    // ---- wave-local transpose: two 16-row halves through the 4KB region ----
    FragU frag[8];
#pragma unroll
    for (int h = 0; h < 2; ++h) {
#pragma unroll
      for (int i = 0; i < 8; ++i) {
        int rowp = 2 * i + hi;           // LDS-local row 0..15 (global row 16h+rowp)
        float4 v = xr[8 * h + i];
        *(uint2*)&lds[hbase + rowp * 256 + ((((l31 >> 1) ^ rowp) << 4)) + (l31 & 1) * 8] =
            make_uint2(cvtpk(v.x, v.y), cvtpk(v.z, v.w));
      }
      if ((l31 >> 4) == h) {             // my row lives in this half
        const int rowp = l31 & 15;
#pragma unroll
        for (int s = 0; s < 8; ++s)
          frag[s].v = *(const s16x8*)&lds[hbase + rowp * 256 + (((2 * s + hi) ^ rowp) << 4)];
      }
    }

    // ---- 3 fused layers (k-permuted weights; no inter-layer exchange) ----
    f32x16 accs[4];
#pragma unroll
    for (int L = 0; L < 3; ++L) {
      const int wb = L * 32768 + l31 * 256;
#pragma unroll
      for (int cg = 0; cg < 4; ++cg) {
        f32x16 z = {0,0,0,0,0,0,0,0,0,0,0,0,0,0,0,0};
        accs[cg] = z;
      }
      __builtin_amdgcn_s_setprio(1);
#pragma unroll
      for (int s = 0; s < 8; ++s) {
#pragma unroll
        for (int cg = 0; cg < 4; ++cg) {
          const s16x8 a =
              *(const s16x8*)&lds[wb + cg * 8192 + (((2 * s + hi) ^ swz) << 4)];
          if (L < 2)
            accs[cg] = __builtin_amdgcn_mfma_f32_32x32x16_bf16(a, frag[s].v, accs[cg], 0, 0, 0);
          else  // swapped: D = h2 . W2'^T, lane = out-channel, rows in regs
            accs[cg] = __builtin_amdgcn_mfma_f32_32x32x16_bf16(frag[s].v, a, accs[cg], 0, 0, 0);
        }
      }
      __builtin_amdgcn_s_setprio(0);
      if (L < 2) {
        // bias + relu, pack straight into next-layer frags (chi k-order)
#pragma unroll
        for (int cg = 0; cg < 4; ++cg) {
          float tr[16];
#pragma unroll
          for (int q = 0; q < 4; ++q) {
            int ch = cg * 32 + 4 * hi + 8 * q;   // C/D: c = (r&3) + 8*(r>>2) + 4*hi
            const float4 bb = *(const float4*)&bias_lds[L * 128 + ch];
            tr[4 * q + 0] = fmaxf(accs[cg][4 * q + 0] + bb.x, 0.f);
            tr[4 * q + 1] = fmaxf(accs[cg][4 * q + 1] + bb.y, 0.f);
            tr[4 * q + 2] = fmaxf(accs[cg][4 * q + 2] + bb.z, 0.f);
            tr[4 * q + 3] = fmaxf(accs[cg][4 * q + 3] + bb.w, 0.f);
          }
#pragma unroll
          for (int kh = 0; kh < 2; ++kh) {
            frag[2 * cg + kh].u[0] = cvtpk(tr[8 * kh + 0], tr[8 * kh + 1]);
            frag[2 * cg + kh].u[1] = cvtpk(tr[8 * kh + 2], tr[8 * kh + 3]);
            frag[2 * cg + kh].u[2] = cvtpk(tr[8 * kh + 4], tr[8 * kh + 5]);
            frag[2 * cg + kh].u[3] = cvtpk(tr[8 * kh + 6], tr[8 * kh + 7]);
          }
        }
      }
    }

    // ---- segment phase, in-register (lane = channel cg*32+l31; 16 rows in regs) ----
    // row of accs[cg][rg] (global within tile) = (rg&3) + 8*(rg>>2) + 4*hi
    const int nvalid = min(N - tile * 32, 32);
    const int sid0 = __builtin_amdgcn_readlane(scur, 0);
    const int sidL = __builtin_amdgcn_readlane(scur, nvalid - 1);
#pragma unroll
    for (int cg = 0; cg < 4; ++cg)
#pragma unroll
      for (int rg = 0; rg < 16; ++rg)
        accs[cg][rg] = fmaxf(accs[cg][rg] + bias2[cg], 0.f);

    if (nvalid == 32 && sid0 == sidL) {
      // fast path: whole tile in one segment
#pragma unroll
      for (int cg = 0; cg < 4; ++cg) {
        float s = 0.f, mx = 0.f;
#pragma unroll
        for (int rg = 0; rg < 16; ++rg) { s += accs[cg][rg]; mx = fmaxf(mx, accs[cg][rg]); }
        float ps = __int_as_float(__builtin_amdgcn_ds_bpermute(xaddr, __float_as_int(s)));
        float pm = __int_as_float(__builtin_amdgcn_ds_bpermute(xaddr, __float_as_int(mx)));
        s += ps; mx = fmaxf(mx, pm);
        if (!hi) {
          atomicAdd(&seg_sum[sid0 * 128 + cg * 32 + l31], s);
          atomicMax(&seg_max[sid0 * 128 + cg * 32 + l31], __float_as_int(mx));
        }
      }
      if (lane == 0) atomicAdd(&seg_cnt[sid0], 32u);
    } else {
      // slow path: per-row sids via bpermute, loop over the (small) sid range
      int srow[16];
#pragma unroll
      for (int rg = 0; rg < 16; ++rg) {
        int m = (rg & 3) + 8 * (rg >> 2) + 4 * hi;
        srow[rg] = __builtin_amdgcn_ds_bpermute(m << 2, scur);
      }
      for (int sg = sid0; sg <= sidL; ++sg) {
#pragma unroll
        for (int cg = 0; cg < 4; ++cg) {
          float s = 0.f, mx = 0.f;
#pragma unroll
          for (int rg = 0; rg < 16; ++rg) {
            float v = (srow[rg] == sg) ? accs[cg][rg] : 0.f;
            s += v; mx = fmaxf(mx, v);
          }
          float ps = __int_as_float(__builtin_amdgcn_ds_bpermute(xaddr, __float_as_int(s)));
          float pm = __int_as_float(__builtin_amdgcn_ds_bpermute(xaddr, __float_as_int(mx)));
          s += ps; mx = fmaxf(mx, pm);
          if (!hi) {
            atomicAdd(&seg_sum[sg * 128 + cg * 32 + l31], s);
            atomicMax(&seg_max[sg * 128 + cg * 32 + l31], __float_as_int(mx));
          }
        }
        u32 c = (u32)__popcll(__ballot(hi == 0 && scur == sg));
        if (lane == 0) atomicAdd(&seg_cnt[sg], c);
      }
    }
  }
}

// out[s,o] = BN( [sum|max|mean] @ Wo^T + bo )
__global__ __launch_bounds__(128)
void proj_kernel(const float* __restrict__ seg_sum, const unsigned* __restrict__ seg_max,
                 const u32* __restrict__ seg_cnt,
                 const float* __restrict__ Wo, const float* __restrict__ bo,
                 const float* __restrict__ go, const float* __restrict__ beo,
                 const float* __restrict__ mo, const float* __restrict__ vo,
                 float* __restrict__ out) {
  __shared__ __attribute__((aligned(16))) float agg[384];
  __shared__ float part[64];
  const int s = blockIdx.x, t = threadIdx.x;
  float cinv = 1.f / fmaxf((float)seg_cnt[s], 1.f);
  for (int i = t; i < 384; i += 128) {
    float v;
    if (i < 128)      v = seg_sum[s * 128 + i];
    else if (i < 256) v = __uint_as_float(seg_max[s * 128 + i - 128]);
    else              v = seg_sum[s * 128 + i - 256] * cinv;
    agg[i] = v;
  }
  __syncthreads();
  const int o = t & 63, hf = t >> 6;
  const float4* wrow = (const float4*)(Wo + o * 384 + hf * 192);
  float acc = 0.f;
#pragma unroll 8
  for (int k4 = 0; k4 < 48; ++k4) {
    float4 w = wrow[k4];
    float4 a = *(const float4*)&agg[hf * 192 + k4 * 4];
    acc += w.x * a.x + w.y * a.y + w.z * a.z + w.w * a.w;
  }
  if (hf) part[o] = acc;
  __syncthreads();
  if (!hf) {
    acc += part[o];
    float sc = go[o] * rsqrtf(vo[o] + EPSF);
    out[s * 64 + o] = (acc + bo[o] - mo[o]) * sc + beo[o];
  }
}

extern "C" void kernel_launch(void* const* d_in, const int* in_sizes, int n_in,
                              void* d_out, int out_size, void* d_ws, size_t ws_size,
                              hipStream_t stream) {
  (void)n_in; (void)out_size; (void)ws_size;
  const float* x = (const float*)d_in[0];
  const int* batch = (const int*)d_in[1];
  LayerP P0{(const float*)d_in[2],  (const float*)d_in[3],  (const float*)d_in[4],
            (const float*)d_in[5],  (const float*)d_in[6],  (const float*)d_in[7]};
  LayerP P1{(const float*)d_in[8],  (const float*)d_in[9],  (const float*)d_in[10],
            (const float*)d_in[11], (const float*)d_in[12], (const float*)d_in[13]};
  LayerP P2{(const float*)d_in[14], (const float*)d_in[15], (const float*)d_in[16],
            (const float*)d_in[17], (const float*)d_in[18], (const float*)d_in[19]};
  const float* Wo  = (const float*)d_in[20];
  const float* bo  = (const float*)d_in[21];
  const float* go  = (const float*)d_in[22];
  const float* beo = (const float*)d_in[23];
  const float* mo  = (const float*)d_in[24];
  const float* vo  = (const float*)d_in[25];
  const int N = in_sizes[0] / 128;

  char* ws = (char*)d_ws;
  float* seg_sum = (float*)ws;                         // 1 MiB
  int*   seg_max = (int*)(ws + (1u << 20));            // 1 MiB (float bits, >=0)
  u32*   seg_cnt = (u32*)(ws + (2u << 20));            // 8 KiB
  unsigned short* wsW = (unsigned short*)(ws + (2u << 20) + 8192);  // 96 KiB
  float* biasf = (float*)(ws + (2u << 20) + 8192 + 98304);          // 1.5 KiB

  const int n16 = ((2 << 20) + 8192) / 16;
  zero_kernel<<<(n16 + 255) / 256, 256, 0, stream>>>((uint4*)d_ws, n16);
  prep_kernel<<<3, 256, 0, stream>>>(P0, P1, P2, wsW, biasf);
  const int ntiles = (N + 31) / 32;
  enc_kernel<<<NBLK, NTHR, 0, stream>>>(x, batch, wsW, biasf, seg_sum, seg_max, seg_cnt,
                                        N, ntiles);
  proj_kernel<<<NSEG, 128, 0, stream>>>(seg_sum, (const unsigned*)seg_max, seg_cnt,
                                        Wo, bo, go, beo, mo, vo, (float*)d_out);
}

// Round 19
// 103.144 us; speedup vs baseline: 1.6884x; 1.0405x over previous
//
#include <hip/hip_runtime.h>

#define EPSF 1e-5f
#define NSEG 2048
#define NTHR 768     // 12 waves
#define NWAVE 12
#define NBLK 256

typedef short s16x8 __attribute__((ext_vector_type(8)));
typedef float f32x16 __attribute__((ext_vector_type(16)));
typedef unsigned u32;

__device__ __forceinline__ u32 f2bfu(float f) {
  u32 u = __float_as_uint(f);
  u += 0x7FFFu + ((u >> 16) & 1u);  // RNE; no NaN/Inf in data
  return u >> 16;
}
__device__ __forceinline__ u32 pk2(float a, float b) {  // prep path only
  return f2bfu(a) | (f2bfu(b) << 16);
}
// v_cvt_pk_bf16_f32: dst = {lo=bf16(a), hi=bf16(b)} — 1 VALU op
__device__ __forceinline__ u32 cvtpk(float a, float b) {
  u32 r;
  asm("v_cvt_pk_bf16_f32 %0, %1, %2" : "=v"(r) : "v"(a), "v"(b));
  return r;
}

union FragU { s16x8 v; u32 u[4]; };

struct LayerP { const float *W, *b, *g, *be, *m, *v; };

// Fused setup: blocks 0..2 fold BN into weights (bf16; layers 1,2 K-PERMUTED by
// chi(s,hi,j) = 32*(s>>1)+16*(s&1)+4*hi+(j<4 ? j : j+4), the k-order a lane holds
// after the previous layer's MFMA) and compute biases; blocks 3..516 zero the
// 2.1MB seg accumulator region (disjoint writes; one launch instead of two).
__global__ void setup_kernel(LayerP p0, LayerP p1, LayerP p2,
                             unsigned short* __restrict__ wsW,
                             float* __restrict__ biasf,
                             uint4* __restrict__ zp, int n16) {
  const int b = blockIdx.x;
  const int t = threadIdx.x;
  if (b >= 3) {
    int i = (b - 3) * 256 + t;
    if (i < n16) zp[i] = make_uint4(0u, 0u, 0u, 0u);
    return;
  }
  const int L = b;
  LayerP p = (L == 0) ? p0 : ((L == 1) ? p1 : p2);
  uint2* wdst = (uint2*)(wsW + L * 16384);
  for (int i = 0; i < 8; ++i) {
    int cid = t + i * 256;             // 2048 chunks = 128 rows x 16 chunks(16B)
    int row = cid >> 4, ch = cid & 15;
    float s = p.g[row] * rsqrtf(p.v[row] + EPSF);
    float w[8];
    if (L == 0) {                      // natural order: chunk ch = k 8ch..8ch+7
      const float4* s4 = (const float4*)(p.W + row * 128 + ch * 8);
      float4 a = s4[0], bq = s4[1];
      w[0]=a.x; w[1]=a.y; w[2]=a.z; w[3]=a.w; w[4]=bq.x; w[5]=bq.y; w[6]=bq.z; w[7]=bq.w;
    } else {                           // chi-permuted: chunk ch = (2s'+hi)
      int sp = ch >> 1, hi = ch & 1;
      int kb = 32 * (sp >> 1) + 16 * (sp & 1) + 4 * hi;
      const float* src = p.W + row * 128;
      w[0]=src[kb+0]; w[1]=src[kb+1]; w[2]=src[kb+2];  w[3]=src[kb+3];
      w[4]=src[kb+8]; w[5]=src[kb+9]; w[6]=src[kb+10]; w[7]=src[kb+11];
    }
    wdst[cid * 2 + 0] = make_uint2(pk2(w[0]*s, w[1]*s), pk2(w[2]*s, w[3]*s));
    wdst[cid * 2 + 1] = make_uint2(pk2(w[4]*s, w[5]*s), pk2(w[6]*s, w[7]*s));
  }
  if (t < 128) {
    float s = p.g[t] * rsqrtf(p.v[t] + EPSF);
    biasf[L * 128 + t] = p.b[t] * s + p.be[t] - p.m[t] * s;
  }
}

// Barrier-free persistent encoder — EXACT round-16 kernel (proven best, 105.6-107.3us,
// 84 VGPR + 64 AGPR at 3 waves/SIMD, no spill; setprio +4%). Register law
// (4x confirmed): the envelope is exactly full — NO cross-tile prefetch of any
// size fits. Loads at tile top; xr dies at the transpose before accs come alive.
// Scattered direct-frag loads (dropping the transpose) cap at ~900 GB/s (r5-r8) — rejected.
// L0/L1: D = W'.h (lane = x-row), k-permuted weights -> no lane exchange.
// L2: operand-swapped mfma(frag, w) -> lane = OUT CHANNEL, rows in regs:
//     segment sum/max reduce in-register, one bpermute, atomics flush.
// LDS: [0,98304) swizzled weights; [98304,147456) 12x4KB transpose regions.
__global__ __launch_bounds__(NTHR) __attribute__((amdgpu_waves_per_eu(3, 3)))
void enc_kernel(const float* __restrict__ x, const int* __restrict__ batch,
                const unsigned short* __restrict__ wsW, const float* __restrict__ biasf,
                float* __restrict__ seg_sum, int* __restrict__ seg_max,
                u32* __restrict__ seg_cnt, int N, int ntiles) {
  __shared__ __attribute__((aligned(16))) unsigned char lds[98304 + NWAVE * 4096];
  __shared__ __attribute__((aligned(16))) float bias_lds[384];
  const int t = threadIdx.x;
  const int lane = t & 63, wv = t >> 6;
  const int l31 = lane & 31, hi = lane >> 5;
  const int swz = l31 & 15;
  const int xaddr = (lane ^ 32) << 2;  // ds_bpermute addr (segment phase only)

  // one-time: stage weights global->LDS with chunk^row swizzle
  {
    const uint4* src = (const uint4*)wsW;
#pragma unroll
    for (int i = 0; i < 8; ++i) {
      int idx = t + i * NTHR;          // 6144 x 16B
      int byte = idx << 4;
      int dst = byte ^ (((byte >> 8) & 15) << 4);  // chunk ^= row&15
      *(uint4*)&lds[dst] = src[idx];
    }
  }
  if (t < 384) bias_lds[t] = biasf[t];
  __syncthreads();                      // the only block barrier

  // L2 bias per-lane (channel cg*32+l31), hoisted out of the tile loop
  float bias2[4];
#pragma unroll
  for (int cg = 0; cg < 4; ++cg) bias2[cg] = bias_lds[256 + cg * 32 + l31];

  const int hbase = 98304 + wv * 4096;
  const float4* x4 = (const float4*)x;

  // contiguous balanced tile range for this wave
  const int w = blockIdx.x * NWAVE + wv;         // 0..3071
  const int TW = NBLK * NWAVE;                   // 3072
  const int base = ntiles / TW, rem = ntiles % TW;
  const int t0 = w * base + (w < rem ? w : rem);
  const int t1 = t0 + base + (w < rem ? 1 : 0);

  for (int tile = t0; tile < t1; ++tile) {
    // ---- coalesced tile load: instr i = bytes [i*1024,(i+1)*1024), lane*16 within ----
    const bool full = (tile * 32 + 32 <= N);
    float4 xr[16];
    {
      const float4* xt = x4 + (size_t)tile * 1024 + lane;
#pragma unroll
      for (int i = 0; i < 16; ++i)
        xr[i] = full ? xt[i * 64] : make_float4(0.f, 0.f, 0.f, 0.f);
    }
    int rr = tile * 32 + l31;
    const int scur = (rr < N) ? batch[rr] : -1;

    // ---- wave-local transpose: two 16-row halves through the 4KB region ----
    FragU frag[8];
#pragma unroll
    for (int h = 0; h < 2; ++h) {
#pragma unroll
      for (int i = 0; i < 8; ++i) {
        int rowp = 2 * i + hi;           // LDS-local row 0..15 (global row 16h+rowp)
        float4 v = xr[8 * h + i];
        *(uint2*)&lds[hbase + rowp * 256 + ((((l31 >> 1) ^ rowp) << 4)) + (l31 & 1) * 8] =
            make_uint2(cvtpk(v.x, v.y), cvtpk(v.z, v.w));
      }
      if ((l31 >> 4) == h) {             // my row lives in this half
        const int rowp = l31 & 15;
#pragma unroll
        for (int s = 0; s < 8; ++s)
          frag[s].v = *(const s16x8*)&lds[hbase + rowp * 256 + (((2 * s + hi) ^ rowp) << 4)];
      }
    }

    // ---- 3 fused layers (k-permuted weights; no inter-layer exchange) ----
    f32x16 accs[4];
#pragma unroll
    for (int L = 0; L < 3; ++L) {
      const int wb = L * 32768 + l31 * 256;
#pragma unroll
      for (int cg = 0; cg < 4; ++cg) {
        f32x16 z = {0,0,0,0,0,0,0,0,0,0,0,0,0,0,0,0};
        accs[cg] = z;
      }
      __builtin_amdgcn_s_setprio(1);
#pragma unroll
      for (int s = 0; s < 8; ++s) {
#pragma unroll
        for (int cg = 0; cg < 4; ++cg) {
          const s16x8 a =
              *(const s16x8*)&lds[wb + cg * 8192 + (((2 * s + hi) ^ swz) << 4)];
          if (L < 2)
            accs[cg] = __builtin_amdgcn_mfma_f32_32x32x16_bf16(a, frag[s].v, accs[cg], 0, 0, 0);
          else  // swapped: D = h2 . W2'^T, lane = out-channel, rows in regs
            accs[cg] = __builtin_amdgcn_mfma_f32_32x32x16_bf16(frag[s].v, a, accs[cg], 0, 0, 0);
        }
      }
      __builtin_amdgcn_s_setprio(0);
      if (L < 2) {
        // bias + relu, pack straight into next-layer frags (chi k-order)
#pragma unroll
        for (int cg = 0; cg < 4; ++cg) {
          float tr[16];
#pragma unroll
          for (int q = 0; q < 4; ++q) {
            int ch = cg * 32 + 4 * hi + 8 * q;   // C/D: c = (r&3) + 8*(r>>2) + 4*hi
            const float4 bb = *(const float4*)&bias_lds[L * 128 + ch];
            tr[4 * q + 0] = fmaxf(accs[cg][4 * q + 0] + bb.x, 0.f);
            tr[4 * q + 1] = fmaxf(accs[cg][4 * q + 1] + bb.y, 0.f);
            tr[4 * q + 2] = fmaxf(accs[cg][4 * q + 2] + bb.z, 0.f);
            tr[4 * q + 3] = fmaxf(accs[cg][4 * q + 3] + bb.w, 0.f);
          }
#pragma unroll
          for (int kh = 0; kh < 2; ++kh) {
            frag[2 * cg + kh].u[0] = cvtpk(tr[8 * kh + 0], tr[8 * kh + 1]);
            frag[2 * cg + kh].u[1] = cvtpk(tr[8 * kh + 2], tr[8 * kh + 3]);
            frag[2 * cg + kh].u[2] = cvtpk(tr[8 * kh + 4], tr[8 * kh + 5]);
            frag[2 * cg + kh].u[3] = cvtpk(tr[8 * kh + 6], tr[8 * kh + 7]);
          }
        }
      }
    }

    // ---- segment phase, in-register (lane = channel cg*32+l31; 16 rows in regs) ----
    // row of accs[cg][rg] (global within tile) = (rg&3) + 8*(rg>>2) + 4*hi
    const int nvalid = min(N - tile * 32, 32);
    const int sid0 = __builtin_amdgcn_readlane(scur, 0);
    const int sidL = __builtin_amdgcn_readlane(scur, nvalid - 1);
#pragma unroll
    for (int cg = 0; cg < 4; ++cg)
#pragma unroll
      for (int rg = 0; rg < 16; ++rg)
        accs[cg][rg] = fmaxf(accs[cg][rg] + bias2[cg], 0.f);

    if (nvalid == 32 && sid0 == sidL) {
      // fast path: whole tile in one segment
#pragma unroll
      for (int cg = 0; cg < 4; ++cg) {
        float s = 0.f, mx = 0.f;
#pragma unroll
        for (int rg = 0; rg < 16; ++rg) { s += accs[cg][rg]; mx = fmaxf(mx, accs[cg][rg]); }
        float ps = __int_as_float(__builtin_amdgcn_ds_bpermute(xaddr, __float_as_int(s)));
        float pm = __int_as_float(__builtin_amdgcn_ds_bpermute(xaddr, __float_as_int(mx)));
        s += ps; mx = fmaxf(mx, pm);
        if (!hi) {
          atomicAdd(&seg_sum[sid0 * 128 + cg * 32 + l31], s);
          atomicMax(&seg_max[sid0 * 128 + cg * 32 + l31], __float_as_int(mx));
        }
      }
      if (lane == 0) atomicAdd(&seg_cnt[sid0], 32u);
    } else {
      // slow path: per-row sids via bpermute, loop over the (small) sid range
      int srow[16];
#pragma unroll
      for (int rg = 0; rg < 16; ++rg) {
        int m = (rg & 3) + 8 * (rg >> 2) + 4 * hi;
        srow[rg] = __builtin_amdgcn_ds_bpermute(m << 2, scur);
      }
      for (int sg = sid0; sg <= sidL; ++sg) {
#pragma unroll
        for (int cg = 0; cg < 4; ++cg) {
          float s = 0.f, mx = 0.f;
#pragma unroll
          for (int rg = 0; rg < 16; ++rg) {
            float v = (srow[rg] == sg) ? accs[cg][rg] : 0.f;
            s += v; mx = fmaxf(mx, v);
          }
          float ps = __int_as_float(__builtin_amdgcn_ds_bpermute(xaddr, __float_as_int(s)));
          float pm = __int_as_float(__builtin_amdgcn_ds_bpermute(xaddr, __float_as_int(mx)));
          s += ps; mx = fmaxf(mx, pm);
          if (!hi) {
            atomicAdd(&seg_sum[sg * 128 + cg * 32 + l31], s);
            atomicMax(&seg_max[sg * 128 + cg * 32 + l31], __float_as_int(mx));
          }
        }
        u32 c = (u32)__popcll(__ballot(hi == 0 && scur == sg));
        if (lane == 0) atomicAdd(&seg_cnt[sg], c);
      }
    }
  }
}

// out[s,o] = BN( [sum|max|mean] @ Wo^T + bo )
__global__ __launch_bounds__(128)
void proj_kernel(const float* __restrict__ seg_sum, const unsigned* __restrict__ seg_max,
                 const u32* __restrict__ seg_cnt,
                 const float* __restrict__ Wo, const float* __restrict__ bo,
                 const float* __restrict__ go, const float* __restrict__ beo,
                 const float* __restrict__ mo, const float* __restrict__ vo,
                 float* __restrict__ out) {
  __shared__ __attribute__((aligned(16))) float agg[384];
  __shared__ float part[64];
  const int s = blockIdx.x, t = threadIdx.x;
  float cinv = 1.f / fmaxf((float)seg_cnt[s], 1.f);
  for (int i = t; i < 384; i += 128) {
    float v;
    if (i < 128)      v = seg_sum[s * 128 + i];
    else if (i < 256) v = __uint_as_float(seg_max[s * 128 + i - 128]);
    else              v = seg_sum[s * 128 + i - 256] * cinv;
    agg[i] = v;
  }
  __syncthreads();
  const int o = t & 63, hf = t >> 6;
  const float4* wrow = (const float4*)(Wo + o * 384 + hf * 192);
  float acc = 0.f;
#pragma unroll 8
  for (int k4 = 0; k4 < 48; ++k4) {
    float4 w = wrow[k4];
    float4 a = *(const float4*)&agg[hf * 192 + k4 * 4];
    acc += w.x * a.x + w.y * a.y + w.z * a.z + w.w * a.w;
  }
  if (hf) part[o] = acc;
  __syncthreads();
  if (!hf) {
    acc += part[o];
    float sc = go[o] * rsqrtf(vo[o] + EPSF);
    out[s * 64 + o] = (acc + bo[o] - mo[o]) * sc + beo[o];
  }
}

extern "C" void kernel_launch(void* const* d_in, const int* in_sizes, int n_in,
                              void* d_out, int out_size, void* d_ws, size_t ws_size,
                              hipStream_t stream) {
  (void)n_in; (void)out_size; (void)ws_size;
  const float* x = (const float*)d_in[0];
  const int* batch = (const int*)d_in[1];
  LayerP P0{(const float*)d_in[2],  (const float*)d_in[3],  (const float*)d_in[4],
            (const float*)d_in[5],  (const float*)d_in[6],  (const float*)d_in[7]};
  LayerP P1{(const float*)d_in[8],  (const float*)d_in[9],  (const float*)d_in[10],
            (const float*)d_in[11], (const float*)d_in[12], (const float*)d_in[13]};
  LayerP P2{(const float*)d_in[14], (const float*)d_in[15], (const float*)d_in[16],
            (const float*)d_in[17], (const float*)d_in[18], (const float*)d_in[19]};
  const float* Wo  = (const float*)d_in[20];
  const float* bo  = (const float*)d_in[21];
  const float* go  = (const float*)d_in[22];
  const float* beo = (const float*)d_in[23];
  const float* mo  = (const float*)d_in[24];
  const float* vo  = (const float*)d_in[25];
  const int N = in_sizes[0] / 128;

  char* ws = (char*)d_ws;
  float* seg_sum = (float*)ws;                         // 1 MiB
  int*   seg_max = (int*)(ws + (1u << 20));            // 1 MiB (float bits, >=0)
  u32*   seg_cnt = (u32*)(ws + (2u << 20));            // 8 KiB
  unsigned short* wsW = (unsigned short*)(ws + (2u << 20) + 8192);  // 96 KiB
  float* biasf = (float*)(ws + (2u << 20) + 8192 + 98304);          // 1.5 KiB

  const int n16 = ((2 << 20) + 8192) / 16;             // 131584 uint4 to zero
  const int nzero_blk = (n16 + 255) / 256;             // 514
  setup_kernel<<<3 + nzero_blk, 256, 0, stream>>>(P0, P1, P2, wsW, biasf,
                                                  (uint4*)d_ws, n16);
  const int ntiles = (N + 31) / 32;
  enc_kernel<<<NBLK, NTHR, 0, stream>>>(x, batch, wsW, biasf, seg_sum, seg_max, seg_cnt,
                                        N, ntiles);
  proj_kernel<<<NSEG, 128, 0, stream>>>(seg_sum, (const unsigned*)seg_max, seg_cnt,
                                        Wo, bo, go, beo, mo, vo, (float*)d_out);
}